// Round 10
// baseline (16769.987 us; speedup 1.0000x reference)
//
#include <hip/hip_runtime.h>
#include <hip/hip_fp16.h>
#include <math.h>

// ESN recurrence, round 10: barrier-free fused wave-autonomous producers.
// Every wave needs the WHOLE state, so the WG barrier adds no dependency --
// only cost (stage + __syncthreads + slowest-poller coupling). R10: 512
// independent 1-wave WGs, 4 rows each. Each wave polls the full 8KB state
// slot (16 u64/lane, its own 32 cols) and FMAs each u64 on tag arrival
// (per-quarter lock-in), then a 7-shfl merged butterfly puts row (lane&3)'s
// full sum in lane 0..3 -> tanh -> one 16B tagged wave-store. No LDS, no
// barriers anywhere in the producer loop.
// History mode (proven in R9): full tagged state history in ws, no ring
// reuse -> no back-pressure, no readers; readout is a post-kernel.
// Tag protocol unchanged: u32 = (tag=t)<<16 | f16(state); stale replay
// entries are bit-identical (deterministic) -> benign; 0xAA poison never
// matches. FMA arrival order varies run-to-run -> fp reorder noise ~1e-6,
// invisible vs 6.8e-2 threshold and the 1.6e-2 f16-quantization absmax.

#define R_    2048
#define I_    32
#define O_    32
#define NSTEP 8191
#define GW    512          // 1-wave workgroups, 4 rows each
#define CAPP  (1u << 24)   // poll cap: fail loud, never hang

typedef unsigned int u32;
typedef unsigned long long u64;

__device__ __forceinline__ float tanh_fast(float u) {
    float e = __expf(2.f * u);            // inf-safe: overflow -> +/-1 exactly
    return 1.f - __fdividef(2.f, e + 1.f);
}
__device__ __forceinline__ u32 pkh(float v, u32 tag) {
    return (tag << 16) | (u32)__half_as_ushort(__float2half(v));
}
__device__ __forceinline__ u64 ald(const u64* p) {
    return __hip_atomic_load(p, __ATOMIC_RELAXED, __HIP_MEMORY_SCOPE_AGENT);
}
__device__ __forceinline__ float h2f(u32 b) {
    return __half2float(__ushort_as_half((unsigned short)(b & 0xFFFFu)));
}

// ws layout: [4096, 4096 + 8192*R_*4) states u32[8192][R_] (67.1 MB; R9
// confirmed ws_size covers this -- hist branch ran and passed)

__global__ __launch_bounds__(256) void esn_init(const float* __restrict__ X,
                                                const float* __restrict__ W_out,
                                                float* __restrict__ out)
{
    int idx = blockIdx.x * blockDim.x + threadIdx.x;
    if (idx < NSTEP * O_) {
        int q = idx >> 5;
        int o = idx & 31;
        const float* wrow = W_out + o * (R_ + I_) + R_;
        const float* xrow = X + q * I_;
        float acc = 0.f;
        #pragma unroll
        for (int j = 0; j < I_; ++j) acc = fmaf(wrow[j], xrow[j], acc);
        out[idx] = acc;   // x-part; state part added by esn_readout
    }
}

// post-pass readout: out[t] += W_out[:, :R] @ s_{t+1}
__global__ __launch_bounds__(256) void esn_readout(const u32* __restrict__ states,
                                                   const float* __restrict__ W_out,
                                                   float* __restrict__ out)
{
    __shared__ float s_arr[R_];
    const int t   = blockIdx.x;        // 0..NSTEP-1
    const int tid = threadIdx.x;
    const u64* p64 = (const u64*)(states + (size_t)(t + 1) * R_);
    #pragma unroll
    for (int q = 0; q < 4; ++q) {
        u64 a = *(const u64*)(&p64[q * 256 + tid]);   // plain load: post-kernel
        float2 f; f.x = h2f((u32)a); f.y = h2f((u32)(a >> 32));
        *reinterpret_cast<float2*>(&s_arr[q * 512 + 2 * tid]) = f;
    }
    __syncthreads();
    const int o = tid >> 3, c = tid & 7;
    const float* wrow = W_out + (size_t)o * (R_ + I_) + c * 256;
    float acc = 0.f;
    #pragma unroll 16
    for (int j = 0; j < 256; j += 4) {
        float4 wv = *reinterpret_cast<const float4*>(wrow + j);
        float4 sv = *reinterpret_cast<const float4*>(&s_arr[c * 256 + j]);
        acc = fmaf(wv.x, sv.x, acc); acc = fmaf(wv.y, sv.y, acc);
        acc = fmaf(wv.z, sv.z, acc); acc = fmaf(wv.w, sv.w, acc);
    }
    acc += __shfl_xor(acc, 1, 64);
    acc += __shfl_xor(acc, 2, 64);
    acc += __shfl_xor(acc, 4, 64);
    if (c == 0) out[t * O_ + o] += acc;
}

// quarter n (n=2k+h, k=0..7, h=0..1): u64 idx k*128 + 2*lane + h,
// cols k*256 + 4*lane + 2h + {0,1}, weights w[i][4k+2h+{0,1}]
#define LOADQ(n) if (pend & (1u << n)) b##n = ald(p64 + ((n >> 1) * 128 + 2 * lane + (n & 1)));
#define CHKQ(n)                                                              \
    if ((pend & (1u << n)) && !((b##n ^ pat) & msk)) {                       \
        const float c0 = h2f((u32)b##n), c1 = h2f((u32)(b##n >> 32));        \
        p0 = fmaf(w[0][4*(n>>1)+2*(n&1)], c0,                                \
             fmaf(w[0][4*(n>>1)+2*(n&1)+1], c1, p0));                        \
        p1 = fmaf(w[1][4*(n>>1)+2*(n&1)], c0,                                \
             fmaf(w[1][4*(n>>1)+2*(n&1)+1], c1, p1));                        \
        p2 = fmaf(w[2][4*(n>>1)+2*(n&1)], c0,                                \
             fmaf(w[2][4*(n>>1)+2*(n&1)+1], c1, p2));                        \
        p3 = fmaf(w[3][4*(n>>1)+2*(n&1)], c0,                                \
             fmaf(w[3][4*(n>>1)+2*(n&1)+1], c1, p3));                        \
        pend &= ~(1u << n);                                                  \
    }

__global__ __launch_bounds__(64)
__attribute__((amdgpu_waves_per_eu(1, 1)))
void esn_main(const float* __restrict__ X, const float* __restrict__ W_in,
              const float* __restrict__ W_res, u32* __restrict__ ring)
{
    const int lane  = threadIdx.x & 63;
    const int g     = blockIdx.x;
    const int myrow = g * 4;              // this wave's 4 rows

    // W_res slice as 128 scalar floats: w[i][4k+j] = row myrow+i,
    // col k*256 + 4*lane + j  (each float4 load: 64 lanes x 16B, coalesced
    // within a 1KB span; 8 chunks cover the row)
    float w[4][32];
    #pragma unroll
    for (int i = 0; i < 4; ++i) {
        const float* wr = W_res + (size_t)(myrow + i) * R_;
        #pragma unroll
        for (int k = 0; k < 8; ++k) {
            float4 v = *reinterpret_cast<const float4*>(wr + k * 256 + 4 * lane);
            w[i][4*k+0] = v.x; w[i][4*k+1] = v.y;
            w[i][4*k+2] = v.z; w[i][4*k+3] = v.w;
        }
    }
    float wi0 = (lane < 32) ? W_in[(size_t)(myrow + 0) * I_ + lane] : 0.f;
    float wi1 = (lane < 32) ? W_in[(size_t)(myrow + 1) * I_ + lane] : 0.f;
    float wi2 = (lane < 32) ? W_in[(size_t)(myrow + 2) * I_ + lane] : 0.f;
    float wi3 = (lane < 32) ? W_in[(size_t)(myrow + 3) * I_ + lane] : 0.f;

    for (int t = 0; t < NSTEP; ++t) {
        // x-part folded into the partials (lane<32 holds col=lane of W_in)
        const float xl = (lane < 32) ? X[(size_t)t * I_ + lane] : 0.f;
        float p0 = wi0 * xl, p1 = wi1 * xl, p2 = wi2 * xl, p3 = wi3 * xl;

        if (t > 0) {   // t==0: s_0 = 0, partials stay at x-part
            const u32 tg  = (u32)t;
            const u64 pat = ((u64)tg << 48) | ((u64)tg << 16);
            const u64 msk = 0xFFFF0000FFFF0000ull;
            const u64* p64 = (const u64*)(ring + (size_t)t * R_);
            u64 b0=0,b1=0,b2=0,b3=0,b4=0,b5=0,b6=0,b7=0,
                b8=0,b9=0,b10=0,b11=0,b12=0,b13=0,b14=0,b15=0;
            u32 pend = 0xFFFFu;
            unsigned tries = 0;
            for (;;) {
                // loads grouped (issue back-to-back), then check+FMA on
                // arrival -- straggler latency hides under arrived FMAs
                LOADQ(0)  LOADQ(1)  LOADQ(2)  LOADQ(3)
                LOADQ(4)  LOADQ(5)  LOADQ(6)  LOADQ(7)
                LOADQ(8)  LOADQ(9)  LOADQ(10) LOADQ(11)
                LOADQ(12) LOADQ(13) LOADQ(14) LOADQ(15)
                CHKQ(0)  CHKQ(1)  CHKQ(2)  CHKQ(3)
                CHKQ(4)  CHKQ(5)  CHKQ(6)  CHKQ(7)
                CHKQ(8)  CHKQ(9)  CHKQ(10) CHKQ(11)
                CHKQ(12) CHKQ(13) CHKQ(14) CHKQ(15)
                if (!pend) break;
                if (++tries > CAPP) break;   // fail loud, never hang
                __builtin_amdgcn_s_sleep(1);
            }
        }

        // merged butterfly: 7 shfl instead of 24. After this, lane l holds
        // row (l&3)'s FULL 2048-col sum (verified mapping in comments):
        //   bit0 merge: a01[l] = sum over pair {l&~1,l|1} of p_{l&1}
        float a01 = (lane & 1) ? p1 : p0;
        float s01 = (lane & 1) ? p0 : p1;
        a01 += __shfl_xor(s01, 1, 64);
        float a23 = (lane & 1) ? p3 : p2;
        float s23 = (lane & 1) ? p2 : p3;
        a23 += __shfl_xor(s23, 1, 64);
        //   bit1 merge: A[l] = sum over 4-lane cluster of row (l&3)
        float A  = (lane & 2) ? a23 : a01;
        float Bv = (lane & 2) ? a01 : a23;
        A += __shfl_xor(Bv, 2, 64);
        //   bits 2..5: full 64-lane reduction
        A += __shfl_xor(A, 4, 64);
        A += __shfl_xor(A, 8, 64);
        A += __shfl_xor(A, 16, 64);
        A += __shfl_xor(A, 32, 64);

        // publish: lanes 0..3 hold rows myrow+0..3 -> one 16B wave-store
        if (lane < 4) {
            __hip_atomic_store(&ring[(size_t)(t + 1) * R_ + myrow + lane],
                               pkh(tanh_fast(A), (u32)(t + 1)),
                               __ATOMIC_RELAXED, __HIP_MEMORY_SCOPE_AGENT);
        }
    }
}

extern "C" void kernel_launch(void* const* d_in, const int* in_sizes, int n_in,
                              void* d_out, int out_size, void* d_ws, size_t ws_size,
                              hipStream_t stream)
{
    (void)in_sizes; (void)n_in; (void)out_size; (void)ws_size;
    const float* X      = (const float*)d_in[0];
    const float* W_in   = (const float*)d_in[1];
    const float* W_res  = (const float*)d_in[2];
    const float* W_out  = (const float*)d_in[3];
    float* out = (float*)d_out;

    u32* ring = (u32*)((char*)d_ws + 4096);

    hipLaunchKernelGGL(esn_init, dim3(1024), dim3(256), 0, stream,
                       X, W_out, out);
    hipLaunchKernelGGL(esn_main, dim3(GW), dim3(64), 0, stream,
                       X, W_in, W_res, ring);
    hipLaunchKernelGGL(esn_readout, dim3(NSTEP), dim3(256), 0, stream,
                       ring, W_out, out);
}

// Round 11
// 15468.414 us; speedup vs baseline: 1.0841x; 1.0841x over previous
//
#include <hip/hip_runtime.h>
#include <hip/hip_fp16.h>
#include <math.h>

// ESN recurrence, round 11: poll-traffic reduction + fused arrival-FMA.
// Congestion law from R3/R9/R10: step time tracks total poll bytes/round
// (R10: 512 WGs x 8KB = 4MB -> 2.05us/step; R9: 128 x 8KB = 1MB -> 1.69;
// this: 64 x 8KB = 512KB). 64 WGs x 512 threads, 32 rows/WG; each thread
// polls exactly the 2 u64 (16B) holding its 4 matvec columns and FMAs each
// on tag arrival (lock-in) -> matvec off the serial path; after the last
// tag: 64 FMA + 32-shfl reduce-scatter + LDS cross-wave sum (1 barrier,
// rotating finalizer wave) + one 128B tagged publish.
// History mode (R9-proven): full tagged state history in ws, no ring reuse,
// no back-pressure, no reader WGs; readout is a post-kernel.
// Tags: u32 = (tag)<<16 | f16(state); poison 0xAAAA never matches; replay-
// stale entries are value-identical up to fp-reorder noise (~1e-6, invisible
// vs 6.8e-2 threshold and 1.6e-2 f16 quantization).

#define R_    2048
#define I_    32
#define O_    32
#define NSTEP 8191
#define GW    64           // producer workgroups
#define BLK   512          // threads per WG (8 waves), 32 rows/WG
#define CAPP  (1u << 24)   // poll cap: fail loud, never hang

typedef unsigned int u32;
typedef unsigned long long u64;

__device__ __forceinline__ float tanh_fast(float u) {
    float e = __expf(2.f * u);            // inf-safe: overflow -> +/-1 exactly
    return 1.f - __fdividef(2.f, e + 1.f);
}
__device__ __forceinline__ u32 pkh(float v, u32 tag) {
    return (tag << 16) | (u32)__half_as_ushort(__float2half(v));
}
__device__ __forceinline__ u64 ald(const u64* p) {
    return __hip_atomic_load(p, __ATOMIC_RELAXED, __HIP_MEMORY_SCOPE_AGENT);
}
__device__ __forceinline__ float h2f(u32 b) {
    return __half2float(__ushort_as_half((unsigned short)(b & 0xFFFFu)));
}

// ws layout: [4096, 4096 + 8192*R_*4) states u32[8192][R_] (67.1 MB;
// hist mode confirmed available since R9)

__global__ __launch_bounds__(256) void esn_init(const float* __restrict__ X,
                                                const float* __restrict__ W_out,
                                                float* __restrict__ out)
{
    int idx = blockIdx.x * blockDim.x + threadIdx.x;
    if (idx < NSTEP * O_) {
        int q = idx >> 5;
        int o = idx & 31;
        const float* wrow = W_out + o * (R_ + I_) + R_;
        const float* xrow = X + q * I_;
        float acc = 0.f;
        #pragma unroll
        for (int j = 0; j < I_; ++j) acc = fmaf(wrow[j], xrow[j], acc);
        out[idx] = acc;   // x-part; state part added by esn_readout
    }
}

// post-pass readout: out[t] += W_out[:, :R] @ s_{t+1}
__global__ __launch_bounds__(256) void esn_readout(const u32* __restrict__ states,
                                                   const float* __restrict__ W_out,
                                                   float* __restrict__ out)
{
    __shared__ float s_arr[R_];
    const int t   = blockIdx.x;        // 0..NSTEP-1
    const int tid = threadIdx.x;
    const u64* p64 = (const u64*)(states + (size_t)(t + 1) * R_);
    #pragma unroll
    for (int q = 0; q < 4; ++q) {
        u64 a = *(const u64*)(&p64[q * 256 + tid]);   // plain load: post-kernel
        float2 f; f.x = h2f((u32)a); f.y = h2f((u32)(a >> 32));
        *reinterpret_cast<float2*>(&s_arr[q * 512 + 2 * tid]) = f;
    }
    __syncthreads();
    const int o = tid >> 3, c = tid & 7;
    const float* wrow = W_out + (size_t)o * (R_ + I_) + c * 256;
    float acc = 0.f;
    #pragma unroll 16
    for (int j = 0; j < 256; j += 4) {
        float4 wv = *reinterpret_cast<const float4*>(wrow + j);
        float4 sv = *reinterpret_cast<const float4*>(&s_arr[c * 256 + j]);
        acc = fmaf(wv.x, sv.x, acc); acc = fmaf(wv.y, sv.y, acc);
        acc = fmaf(wv.z, sv.z, acc); acc = fmaf(wv.w, sv.w, acc);
    }
    acc += __shfl_xor(acc, 1, 64);
    acc += __shfl_xor(acc, 2, 64);
    acc += __shfl_xor(acc, 4, 64);
    if (c == 0) out[t * O_ + o] += acc;
}

__global__ __launch_bounds__(BLK)
__attribute__((amdgpu_waves_per_eu(2, 2)))
void esn_main(const float* __restrict__ X, const float* __restrict__ W_in,
              const float* __restrict__ W_res, u32* __restrict__ ring)
{
    const int tid  = threadIdx.x;         // 0..511
    const int lane = tid & 63;
    const int wave = tid >> 6;            // 0..7
    const int g    = blockIdx.x;          // 0..63
    const int row0 = g * 32;

    __shared__ float pbuf[2][8][32];      // cross-wave row partials (dbuf)

    // W_res slice: thread owns cols {2tid, 2tid+1, 1024+2tid, 1024+2tid+1}
    // for all 32 WG rows -> w[32][4] = 128 scalar VGPRs. Loads: 512 threads
    // x 8B contiguous per (row, half) = fully coalesced.
    float w[32][4];
    #pragma unroll
    for (int r = 0; r < 32; ++r) {
        const float* wr = W_res + (size_t)(row0 + r) * R_;
        float2 u = *reinterpret_cast<const float2*>(wr + 2 * tid);
        float2 v = *reinterpret_cast<const float2*>(wr + 1024 + 2 * tid);
        w[r][0] = u.x; w[r][1] = u.y; w[r][2] = v.x; w[r][3] = v.y;
    }
    // x-part coefficients: wave v covers rows 4v..4v+3 (lane<32 = col lane)
    float wiv[4];
    #pragma unroll
    for (int i = 0; i < 4; ++i)
        wiv[i] = (lane < 32) ? W_in[(size_t)(row0 + 4 * wave + i) * I_ + lane]
                             : 0.f;

    for (int t = 0; t < NSTEP; ++t) {
        const float xl = (lane < 32) ? X[(size_t)t * I_ + lane] : 0.f;

        // partials for all 32 rows; x-part folded in via static-index select
        float part[32];
        #pragma unroll
        for (int r = 0; r < 32; ++r)
            part[r] = ((r >> 2) == wave) ? wiv[r & 3] * xl : 0.f;

        if (t > 0) {   // t==0: s_0 = 0
            const u32 tg  = (u32)t;
            const u64 pat = ((u64)tg << 48) | ((u64)tg << 16);
            const u64 msk = 0xFFFF0000FFFF0000ull;
            const u64* p64 = (const u64*)(ring + (size_t)t * R_);
            u32 pend = 0x3u;
            unsigned tries = 0;
            for (;;) {
                u64 b0 = 0, b1 = 0;
                if (pend & 1u) b0 = ald(p64 + tid);          // cols 2tid,2tid+1
                if (pend & 2u) b1 = ald(p64 + 512 + tid);    // cols 1024+2tid..
                if ((pend & 1u) && !((b0 ^ pat) & msk)) {
                    const float c0 = h2f((u32)b0), c1 = h2f((u32)(b0 >> 32));
                    #pragma unroll
                    for (int r = 0; r < 32; ++r)
                        part[r] = fmaf(w[r][0], c0, fmaf(w[r][1], c1, part[r]));
                    pend &= ~1u;
                }
                if ((pend & 2u) && !((b1 ^ pat) & msk)) {
                    const float c2 = h2f((u32)b1), c3 = h2f((u32)(b1 >> 32));
                    #pragma unroll
                    for (int r = 0; r < 32; ++r)
                        part[r] = fmaf(w[r][2], c2, fmaf(w[r][3], c3, part[r]));
                    pend &= ~2u;
                }
                if (!pend) break;
                if (++tries > CAPP) break;   // fail loud, never hang
                __builtin_amdgcn_s_sleep(1);
            }
        }

        // reduce-scatter butterfly: 32 shfl; after it lane l holds the full
        // 64-lane sum of row (l&31) for this wave's column slice.
        float c16[16];
        #pragma unroll
        for (int j = 0; j < 16; ++j) {
            float keep = (lane & 1) ? part[2*j+1] : part[2*j];
            float give = (lane & 1) ? part[2*j]   : part[2*j+1];
            c16[j] = keep + __shfl_xor(give, 1, 64);
        }
        float c8[8];
        #pragma unroll
        for (int j = 0; j < 8; ++j) {
            float keep = (lane & 2) ? c16[2*j+1] : c16[2*j];
            float give = (lane & 2) ? c16[2*j]   : c16[2*j+1];
            c8[j] = keep + __shfl_xor(give, 2, 64);
        }
        float c4[4];
        #pragma unroll
        for (int j = 0; j < 4; ++j) {
            float keep = (lane & 4) ? c8[2*j+1] : c8[2*j];
            float give = (lane & 4) ? c8[2*j]   : c8[2*j+1];
            c4[j] = keep + __shfl_xor(give, 4, 64);
        }
        float c2[2];
        #pragma unroll
        for (int j = 0; j < 2; ++j) {
            float keep = (lane & 8) ? c4[2*j+1] : c4[2*j];
            float give = (lane & 8) ? c4[2*j]   : c4[2*j+1];
            c2[j] = keep + __shfl_xor(give, 8, 64);
        }
        float keep = (lane & 16) ? c2[1] : c2[0];
        float give = (lane & 16) ? c2[0] : c2[1];
        float c1 = keep + __shfl_xor(give, 16, 64);
        c1 += __shfl_xor(c1, 32, 64);

        if (lane < 32) pbuf[t & 1][wave][lane] = c1;
        __syncthreads();   // one barrier/step; pbuf double-buffered

        // rotating finalizer wave: sum 8 wave partials, tanh, tagged publish
        // (32 lanes x u32 = one 128B transaction). Other waves run ahead into
        // the next poll, which self-synchronizes on data tags.
        if (wave == (t & 7) && lane < 32) {
            float s = pbuf[t & 1][0][lane] + pbuf[t & 1][1][lane]
                    + pbuf[t & 1][2][lane] + pbuf[t & 1][3][lane]
                    + pbuf[t & 1][4][lane] + pbuf[t & 1][5][lane]
                    + pbuf[t & 1][6][lane] + pbuf[t & 1][7][lane];
            __hip_atomic_store(&ring[(size_t)(t + 1) * R_ + row0 + lane],
                               pkh(tanh_fast(s), (u32)(t + 1)),
                               __ATOMIC_RELAXED, __HIP_MEMORY_SCOPE_AGENT);
        }
    }
}

extern "C" void kernel_launch(void* const* d_in, const int* in_sizes, int n_in,
                              void* d_out, int out_size, void* d_ws, size_t ws_size,
                              hipStream_t stream)
{
    (void)in_sizes; (void)n_in; (void)out_size; (void)ws_size;
    const float* X      = (const float*)d_in[0];
    const float* W_in   = (const float*)d_in[1];
    const float* W_res  = (const float*)d_in[2];
    const float* W_out  = (const float*)d_in[3];
    float* out = (float*)d_out;

    u32* ring = (u32*)((char*)d_ws + 4096);

    hipLaunchKernelGGL(esn_init, dim3(1024), dim3(256), 0, stream,
                       X, W_out, out);
    hipLaunchKernelGGL(esn_main, dim3(GW), dim3(BLK), 0, stream,
                       X, W_in, W_res, ring);
    hipLaunchKernelGGL(esn_readout, dim3(NSTEP), dim3(256), 0, stream,
                       ring, W_out, out);
}

// Round 12
// 13018.201 us; speedup vs baseline: 1.2882x; 1.1882x over previous
//
#include <hip/hip_runtime.h>
#include <hip/hip_fp16.h>
#include <math.h>

// ESN recurrence, round 12 = R9 core + poll phase-alignment + lighter reduce.
// R11 falsified the traffic law (half traffic, slower); R9 remains best at
// 1.47us/step of which ~1.1us is DETECT latency quantized in poll-round RTTs:
// the first round's loads are served before the last producer's store is
// visible (~700cy), so detect lands on round 2 (~2 RTT). Fixes:
//  1) calibrated s_sleep(6) (~384cy) before the first poll round -> round 1
//     is served after visibility -> detect ~1 RTT; spin (no sleep) 6 rounds
//     after that so the tail isn't sleep-quantized.
//  2) 7-shfl merged butterfly (R10-proven) instead of 24 shfl.
//  3) esn_init dropped; readout computes the x-part in its c==7 lane before
//     the reduce (one less dispatch, no out[] read-modify-write).
// Core unchanged from R9: 128 WGs x 256 thr, rows g*16..+15 (4/wave), f32
// scalar weights w[4][32], self-validating tagged ring in ws history mode
// (u32 = (tag=t)<<16 | f16; no reuse, no back-pressure, no reader WGs),
// hoisted conditional lock-in polls, LDS dbuf + one barrier/step.
// Replay staleness benign: slot t is rewritten with the SAME tag and
// bit-identical value (deterministic); 0xAA poison tag never matches.

#define R_    2048
#define I_    32
#define O_    32
#define NSTEP 8191
#define G_    128
#define BLK   256
#define CAPP  (1u << 24)   // poll cap: fail loud, never hang

typedef unsigned int u32;
typedef unsigned long long u64;

__device__ __forceinline__ float tanh_fast(float u) {
    float e = __expf(2.f * u);            // inf-safe: overflow -> +/-1 exactly
    return 1.f - __fdividef(2.f, e + 1.f);
}
__device__ __forceinline__ u32 pkh(float v, u32 tag) {
    return (tag << 16) | (u32)__half_as_ushort(__float2half(v));
}
__device__ __forceinline__ u64 ald(const u64* p) {
    return __hip_atomic_load(p, __ATOMIC_RELAXED, __HIP_MEMORY_SCOPE_AGENT);
}
__device__ __forceinline__ float h2f(u32 b) {
    return __half2float(__ushort_as_half((unsigned short)(b & 0xFFFFu)));
}

// ws layout: [4096, 4096 + 8192*R_*4) states u32[8192][R_] (67.1 MB,
// confirmed available since R9)

// post-pass readout: out[t] = W_out[:, :R] @ s_{t+1} + W_out[:, R:] @ x_t
__global__ __launch_bounds__(256) void esn_readout(const u32* __restrict__ states,
                                                   const float* __restrict__ W_out,
                                                   const float* __restrict__ X,
                                                   float* __restrict__ out)
{
    __shared__ float s_arr[R_];
    const int t   = blockIdx.x;        // 0..NSTEP-1
    const int tid = threadIdx.x;
    const u64* p64 = (const u64*)(states + (size_t)(t + 1) * R_);
    #pragma unroll
    for (int q = 0; q < 4; ++q) {
        u64 a = *(const u64*)(&p64[q * 256 + tid]);   // plain load: post-kernel
        float2 f; f.x = h2f((u32)a); f.y = h2f((u32)(a >> 32));
        *reinterpret_cast<float2*>(&s_arr[q * 512 + 2 * tid]) = f;
    }
    __syncthreads();
    const int o = tid >> 3, c = tid & 7;
    const float* wrow = W_out + (size_t)o * (R_ + I_) + c * 256;
    float acc = 0.f;
    #pragma unroll 16
    for (int j = 0; j < 256; j += 4) {
        float4 wv = *reinterpret_cast<const float4*>(wrow + j);
        float4 sv = *reinterpret_cast<const float4*>(&s_arr[c * 256 + j]);
        acc = fmaf(wv.x, sv.x, acc); acc = fmaf(wv.y, sv.y, acc);
        acc = fmaf(wv.z, sv.z, acc); acc = fmaf(wv.w, sv.w, acc);
    }
    if (c == 7) {   // x-part: 32 cols at W_out[o][2048..2079] . X[t]
        const float* wx = W_out + (size_t)o * (R_ + I_) + R_;
        const float* xr = X + (size_t)t * I_;
        #pragma unroll
        for (int j = 0; j < 32; j += 4) {
            float4 wv = *reinterpret_cast<const float4*>(wx + j);
            float4 xv = *reinterpret_cast<const float4*>(xr + j);
            acc = fmaf(wv.x, xv.x, acc); acc = fmaf(wv.y, xv.y, acc);
            acc = fmaf(wv.z, xv.z, acc); acc = fmaf(wv.w, xv.w, acc);
        }
    }
    acc += __shfl_xor(acc, 1, 64);
    acc += __shfl_xor(acc, 2, 64);
    acc += __shfl_xor(acc, 4, 64);
    if (c == 0) out[t * O_ + o] = acc;   // plain assign (no init kernel)
}

__global__ __launch_bounds__(BLK)
__attribute__((amdgpu_waves_per_eu(1, 1)))
void esn_main(const float* __restrict__ X, const float* __restrict__ W_in,
              const float* __restrict__ W_res, const float* __restrict__ state0,
              u32* __restrict__ ring)
{
    const int tid = threadIdx.x;
    const int g   = blockIdx.x;
    __shared__ float s_lds[2][R_];

    const int lane  = tid & 63;
    const int wave  = tid >> 6;
    const int myrow = g * 16 + wave * 4;    // this wave's 4 rows

    // W_res slice as 128 scalar floats:
    // w[i][4k+j] = W_res[myrow+i][k*256 + 4*lane + j]
    float w[4][32];
    #pragma unroll
    for (int i = 0; i < 4; ++i) {
        const float* wr = W_res + (size_t)(myrow + i) * R_;
        #pragma unroll
        for (int k = 0; k < 8; ++k) {
            float4 v = *reinterpret_cast<const float4*>(wr + k * 256 + 4 * lane);
            w[i][4*k+0] = v.x; w[i][4*k+1] = v.y;
            w[i][4*k+2] = v.z; w[i][4*k+3] = v.w;
        }
    }
    float wi[4];
    #pragma unroll
    for (int i = 0; i < 4; ++i)
        wi[i] = (lane < 32) ? W_in[(size_t)(myrow + i) * I_ + lane] : 0.f;

    // seed s_0 into buffer 0
    #pragma unroll
    for (int q = 0; q < 8; ++q)
        s_lds[0][q * 256 + tid] = state0[q * 256 + tid];
    __syncthreads();

    float xl = (lane < 32) ? X[lane] : 0.f;

    for (int t = 0; t < NSTEP; ++t) {
        const float* sbuf = s_lds[t & 1];
        float p0 = wi[0] * xl, p1 = wi[1] * xl, p2 = wi[2] * xl, p3 = wi[3] * xl;
        #pragma unroll
        for (int k = 0; k < 8; ++k) {
            const float4 sv = *reinterpret_cast<const float4*>(
                &sbuf[k * 256 + 4 * lane]);
            p0 = fmaf(w[0][4*k+0], sv.x, p0); p0 = fmaf(w[0][4*k+1], sv.y, p0);
            p0 = fmaf(w[0][4*k+2], sv.z, p0); p0 = fmaf(w[0][4*k+3], sv.w, p0);
            p1 = fmaf(w[1][4*k+0], sv.x, p1); p1 = fmaf(w[1][4*k+1], sv.y, p1);
            p1 = fmaf(w[1][4*k+2], sv.z, p1); p1 = fmaf(w[1][4*k+3], sv.w, p1);
            p2 = fmaf(w[2][4*k+0], sv.x, p2); p2 = fmaf(w[2][4*k+1], sv.y, p2);
            p2 = fmaf(w[2][4*k+2], sv.z, p2); p2 = fmaf(w[2][4*k+3], sv.w, p2);
            p3 = fmaf(w[3][4*k+0], sv.x, p3); p3 = fmaf(w[3][4*k+1], sv.y, p3);
            p3 = fmaf(w[3][4*k+2], sv.z, p3); p3 = fmaf(w[3][4*k+3], sv.w, p3);
        }

        // merged butterfly: 7 shfl; lane l ends holding row (l&3)'s full sum
        // (mapping proven in R10, which passed with this exact sequence)
        float a01 = (lane & 1) ? p1 : p0;
        float s01 = (lane & 1) ? p0 : p1;
        a01 += __shfl_xor(s01, 1, 64);
        float a23 = (lane & 1) ? p3 : p2;
        float s23 = (lane & 1) ? p2 : p3;
        a23 += __shfl_xor(s23, 1, 64);
        float A  = (lane & 2) ? a23 : a01;
        float Bv = (lane & 2) ? a01 : a23;
        A += __shfl_xor(Bv, 2, 64);
        A += __shfl_xor(A, 4, 64);
        A += __shfl_xor(A, 8, 64);
        A += __shfl_xor(A, 16, 64);
        A += __shfl_xor(A, 32, 64);

        // publish: lanes 0..3 store rows myrow+0..3 -> one 16B transaction
        if (lane < 4) {
            __hip_atomic_store(&ring[(size_t)(t + 1) * R_ + myrow + lane],
                               pkh(tanh_fast(A), (u32)(t + 1)),
                               __ATOMIC_RELAXED, __HIP_MEMORY_SCOPE_AGENT);
        }
        if (t == NSTEP - 1) break;

        float xn = (lane < 32) ? X[(size_t)(t + 1) * I_ + lane] : 0.f;

        // poll slot t+1: calibrated pre-sleep aligns round 1 with visibility
        // (~700cy store->visible; sleep ~384cy + load RTT lands after it),
        // then lock-in rounds: spin 6 rounds, then sleep(1) cadence.
        u64 a0 = 0, a1 = 0, a2 = 0, a3 = 0;
        {
            const u32 tg  = (u32)(t + 1);
            const u64 pat = ((u64)tg << 48) | ((u64)tg << 16);
            const u64 msk = 0xFFFF0000FFFF0000ull;
            const u64* p64 = (const u64*)(ring + (size_t)(t + 1) * R_);
            unsigned pend = 0xFu, tries = 0;
            __builtin_amdgcn_s_sleep(6);
            for (;;) {
                u64 b0 = 0, b1 = 0, b2 = 0, b3 = 0;
                if (pend & 1u) b0 = ald(&p64[0 * 256 + tid]);
                if (pend & 2u) b1 = ald(&p64[1 * 256 + tid]);
                if (pend & 4u) b2 = ald(&p64[2 * 256 + tid]);
                if (pend & 8u) b3 = ald(&p64[3 * 256 + tid]);
                if ((pend & 1u) && !((b0 ^ pat) & msk)) { a0 = b0; pend &= ~1u; }
                if ((pend & 2u) && !((b1 ^ pat) & msk)) { a1 = b1; pend &= ~2u; }
                if ((pend & 4u) && !((b2 ^ pat) & msk)) { a2 = b2; pend &= ~4u; }
                if ((pend & 8u) && !((b3 ^ pat) & msk)) { a3 = b3; pend &= ~8u; }
                if (!pend) break;
                if (++tries > CAPP) break;   // fail loud, never hang
                if (tries > 6) __builtin_amdgcn_s_sleep(1);
            }
        }
        // stage into the other buffer
        {
            float* dbuf = s_lds[(t + 1) & 1];
            float2 f;
            f.x = h2f((u32)a0); f.y = h2f((u32)(a0 >> 32));
            *reinterpret_cast<float2*>(&dbuf[0 * 512 + 2 * tid]) = f;
            f.x = h2f((u32)a1); f.y = h2f((u32)(a1 >> 32));
            *reinterpret_cast<float2*>(&dbuf[1 * 512 + 2 * tid]) = f;
            f.x = h2f((u32)a2); f.y = h2f((u32)(a2 >> 32));
            *reinterpret_cast<float2*>(&dbuf[2 * 512 + 2 * tid]) = f;
            f.x = h2f((u32)a3); f.y = h2f((u32)(a3 >> 32));
            *reinterpret_cast<float2*>(&dbuf[3 * 512 + 2 * tid]) = f;
        }
        xl = xn;
        __syncthreads();   // one barrier/step; dbuf proven safe since R5
    }
}

extern "C" void kernel_launch(void* const* d_in, const int* in_sizes, int n_in,
                              void* d_out, int out_size, void* d_ws, size_t ws_size,
                              hipStream_t stream)
{
    (void)in_sizes; (void)n_in; (void)out_size; (void)ws_size;
    const float* X      = (const float*)d_in[0];
    const float* W_in   = (const float*)d_in[1];
    const float* W_res  = (const float*)d_in[2];
    const float* W_out  = (const float*)d_in[3];
    const float* state0 = (const float*)d_in[4];
    float* out = (float*)d_out;

    u32* ring = (u32*)((char*)d_ws + 4096);

    hipLaunchKernelGGL(esn_main, dim3(G_), dim3(BLK), 0, stream,
                       X, W_in, W_res, state0, ring);
    hipLaunchKernelGGL(esn_readout, dim3(NSTEP), dim3(256), 0, stream,
                       ring, W_out, X, out);
}